// Round 4
// baseline (1167.041 us; speedup 1.0000x reference)
//
#include <hip/hip_runtime.h>

#define BATCH 4
#define DIM   1536
#define SEQ   4096
#define NST   16
#define NCHAN (BATCH*DIM)
#define NCH   32       // chunks per sequence
#define CLEN  128      // chunk length
#define T     32       // timesteps per tile: 128B per channel-row per access
#define LBSTR 20       // LDS B/C tile stride ([t][n]); byte row-stride 80 -> float4-aligned reads

#define LOG2E 1.4426950408889634f

// softplus matching jax.nn.softplus = log1p(exp(z)), overflow-safe
__device__ __forceinline__ float softplus_f(float z) {
    return (z > 20.f) ? z : __logf(1.f + __expf(z));
}
__device__ __forceinline__ float exp2_hw(float z) {
    return __builtin_amdgcn_exp2f(z);
}

// DPP quad_perm helper (compile-time control). All lanes active, uniform flow.
template<int CTRL>
__device__ __forceinline__ float dpp_qp(float v) {
    return __int_as_float(
        __builtin_amdgcn_mov_dpp(__float_as_int(v), CTRL, 0xf, 0xf, true));
}
// sum across the 4 lanes of a quad (result in all 4 lanes)
__device__ __forceinline__ float quad_sum(float v) {
    v += dpp_qp<0xB1>(v);   // quad_perm [1,0,3,2]
    v += dpp_qp<0x4E>(v);   // quad_perm [2,3,0,1]
    return v;
}

struct F8 { float4 a, b; };
__device__ __forceinline__ F8 load8(const float* p) {
    F8 r; r.a = *(const float4*)p; r.b = *(const float4*)(p + 4); return r;
}

// ---------------------------------------------------------------------------
// Quad-per-channel decomposition. T=32: every global access (u/delta/B/C/y)
// covers a FULL 128B cache line per row -> no half-line refetch, no
// partial-line writeback. CLEN=128/NCH=32 (round-2 best). 1-tile-deep
// prefetch (tile = 32 steps ~ 2800 cyc of compute cover).
// Lane (q=l>>2, sub=l&3): quad q owns channel; lane owns states sub*4..+3
// and timesteps sub*8..sub*8+7 of each tile.
// ---------------------------------------------------------------------------

// ---------------- Phase A: per-(channel,chunk) summaries ----------------
__global__ __launch_bounds__(256, 6) void ssm_phaseA(
    const float* __restrict__ u, const float* __restrict__ delta,
    const float* __restrict__ Bm, const float* __restrict__ A,
    const float* __restrict__ dbias,
    float* __restrict__ sumdt_out, float* __restrict__ S_out)
{
    constexpr int NT = CLEN / T;   // 4
    __shared__ float lB[4 * T * LBSTR];

    const int tid = threadIdx.x;
    const int w   = tid >> 6;
    const int l   = tid & 63;
    const int q   = l >> 2;       // quad index = channel row in wave = B state row
    const int sub = l & 3;
    const int cj  = sub << 2;     // state group
    const int t8  = sub << 3;     // timestep slot within tile

    const int ch0 = blockIdx.x * 64;
    const int ch  = ch0 + w * 16 + q;
    const int d   = ch % DIM;
    const int bb  = ch0 / DIM;
    const int k   = blockIdx.y;
    const int s0  = k * CLEN;

    float* LB = &lB[w * T * LBSTR];

    float A2[4];
    {
        const float4 av = *(const float4*)(A + (size_t)d * NST + cj);
        A2[0] = av.x * LOG2E; A2[1] = av.y * LOG2E;
        A2[2] = av.z * LOG2E; A2[3] = av.w * LOG2E;
    }
    const float sbias = dbias[d];

    const size_t ubase = (size_t)ch * SEQ + s0;
    const size_t bbase = ((size_t)bb * NST + q) * SEQ + s0;

    F8 PU[2], PD[2], RB;
    PU[0] = load8(u + ubase + t8);
    PD[0] = load8(delta + ubase + t8);
    RB    = load8(Bm + bbase + t8);

    float S[4] = {0.f, 0.f, 0.f, 0.f};
    float sumdt = 0.f;

#pragma unroll
    for (int t = 0; t < NT; ++t) {
        const int cb = t & 1;     // literal after unroll
        const int ss = t * T;

        // stage B tile t: lane writes its 8 timesteps of row q ([t][n] layout)
        {
            const float rb[8] = {RB.a.x, RB.a.y, RB.a.z, RB.a.w,
                                 RB.b.x, RB.b.y, RB.b.z, RB.b.w};
#pragma unroll
            for (int j = 0; j < 8; ++j) LB[(t8 + j) * LBSTR + q] = rb[j];
        }

        // prefetch next tile (full 128B per row)
        if (t + 1 < NT) {
            PU[cb ^ 1] = load8(u + ubase + (ss + T) + t8);
            PD[cb ^ 1] = load8(delta + ubase + (ss + T) + t8);
            RB         = load8(Bm + bbase + (ss + T) + t8);
        }

        const float uc[8] = {PU[cb].a.x, PU[cb].a.y, PU[cb].a.z, PU[cb].a.w,
                             PU[cb].b.x, PU[cb].b.y, PU[cb].b.z, PU[cb].b.w};
        const float dc[8] = {
            softplus_f(PD[cb].a.x + sbias), softplus_f(PD[cb].a.y + sbias),
            softplus_f(PD[cb].a.z + sbias), softplus_f(PD[cb].a.w + sbias),
            softplus_f(PD[cb].b.x + sbias), softplus_f(PD[cb].b.y + sbias),
            softplus_f(PD[cb].b.z + sbias), softplus_f(PD[cb].b.w + sbias)};
        sumdt += ((dc[0] + dc[1]) + (dc[2] + dc[3]))
               + ((dc[4] + dc[5]) + (dc[6] + dc[7]));

#define ASTEP(ii) { \
        const float dt  = dpp_qp<(((ii) >> 3) * 0x55)>(dc[(ii) & 7]); \
        const float uu  = dpp_qp<(((ii) >> 3) * 0x55)>(uc[(ii) & 7]); \
        const float dtu = dt * uu; \
        const float4 bv = *(const float4*)(&LB[(ii) * LBSTR + cj]); \
        S[0] = fmaf(exp2_hw(dt * A2[0]), S[0], dtu * bv.x); \
        S[1] = fmaf(exp2_hw(dt * A2[1]), S[1], dtu * bv.y); \
        S[2] = fmaf(exp2_hw(dt * A2[2]), S[2], dtu * bv.z); \
        S[3] = fmaf(exp2_hw(dt * A2[3]), S[3], dtu * bv.w); \
    }
        ASTEP(0)  ASTEP(1)  ASTEP(2)  ASTEP(3)
        ASTEP(4)  ASTEP(5)  ASTEP(6)  ASTEP(7)
        ASTEP(8)  ASTEP(9)  ASTEP(10) ASTEP(11)
        ASTEP(12) ASTEP(13) ASTEP(14) ASTEP(15)
        ASTEP(16) ASTEP(17) ASTEP(18) ASTEP(19)
        ASTEP(20) ASTEP(21) ASTEP(22) ASTEP(23)
        ASTEP(24) ASTEP(25) ASTEP(26) ASTEP(27)
        ASTEP(28) ASTEP(29) ASTEP(30) ASTEP(31)
#undef ASTEP
    }

    *(float4*)(S_out + ((size_t)k * NCHAN + ch) * NST + cj) =
        make_float4(S[0], S[1], S[2], S[3]);

    const float sfull = quad_sum(sumdt);
    if (sub == 0) sumdt_out[(size_t)k * NCHAN + ch] = sfull;
}

// ---------------- Phase B: scan chunk summaries -> chunk entry states ----
__global__ __launch_bounds__(256) void ssm_phaseB(
    const float* __restrict__ A, const float* __restrict__ sumdt,
    float* __restrict__ S)
{
    const int t  = blockIdx.x * 256 + threadIdx.x;
    const int n  = t & 15;
    const int ch = t >> 4;
    if (ch >= NCHAN) return;
    const int d = ch % DIM;
    const float An2 = A[(size_t)d * NST + n] * LOG2E;

    const size_t kstride = (size_t)NCHAN * NST;
    size_t idx = (size_t)ch * NST + n;

    float x = 0.f;
    float s_nxt = S[idx];
    float p_nxt = sumdt[ch];
#pragma unroll 4
    for (int k = 0; k < NCH; k++) {
        const float s_old = s_nxt;
        const float pdt   = p_nxt;
        if (k + 1 < NCH) {
            s_nxt = S[idx + kstride];
            p_nxt = sumdt[(size_t)(k + 1) * NCHAN + ch];
        }
        S[idx] = x;                                   // x0 for chunk k
        x = fmaf(exp2_hw(An2 * pdt), x, s_old);       // state after chunk k
        idx += kstride;
    }
}

// ---------------- Phase C: replay chunk from x0, emit y ------------------
__global__ __launch_bounds__(256, 5) void ssm_phaseC(
    const float* __restrict__ u, const float* __restrict__ delta,
    const float* __restrict__ Bm, const float* __restrict__ Cm,
    const float* __restrict__ A, const float* __restrict__ Dv,
    const float* __restrict__ dbias, const float* __restrict__ x0,
    float* __restrict__ y)
{
    constexpr int NT = CLEN / T;
    __shared__ float lB[4 * T * LBSTR];
    __shared__ float lC[4 * T * LBSTR];

    const int tid = threadIdx.x;
    const int w   = tid >> 6;
    const int l   = tid & 63;
    const int q   = l >> 2;
    const int sub = l & 3;
    const int cj  = sub << 2;
    const int t8  = sub << 3;

    const int ch0 = blockIdx.x * 64;
    const int ch  = ch0 + w * 16 + q;
    const int d   = ch % DIM;
    const int bb  = ch0 / DIM;
    const int k   = blockIdx.y;
    const int s0  = k * CLEN;

    float* LB = &lB[w * T * LBSTR];
    float* LC = &lC[w * T * LBSTR];

    float A2[4];
    {
        const float4 av = *(const float4*)(A + (size_t)d * NST + cj);
        A2[0] = av.x * LOG2E; A2[1] = av.y * LOG2E;
        A2[2] = av.z * LOG2E; A2[3] = av.w * LOG2E;
    }
    const float sbias = dbias[d];
    const float Dval  = Dv[d];

    float x[4];
    {
        const float4 xv = *(const float4*)(x0 + ((size_t)k * NCHAN + ch) * NST + cj);
        x[0] = xv.x; x[1] = xv.y; x[2] = xv.z; x[3] = xv.w;
    }

    const size_t ubase = (size_t)ch * SEQ + s0;
    const size_t bbase = ((size_t)bb * NST + q) * SEQ + s0;

    F8 PU[2], PD[2], RB, RC;
    PU[0] = load8(u + ubase + t8);
    PD[0] = load8(delta + ubase + t8);
    RB    = load8(Bm + bbase + t8);
    RC    = load8(Cm + bbase + t8);

#pragma unroll
    for (int t = 0; t < NT; ++t) {
        const int cb = t & 1;
        const int ss = t * T;

        {
            const float rb[8] = {RB.a.x, RB.a.y, RB.a.z, RB.a.w,
                                 RB.b.x, RB.b.y, RB.b.z, RB.b.w};
            const float rc[8] = {RC.a.x, RC.a.y, RC.a.z, RC.a.w,
                                 RC.b.x, RC.b.y, RC.b.z, RC.b.w};
#pragma unroll
            for (int j = 0; j < 8; ++j) {
                LB[(t8 + j) * LBSTR + q] = rb[j];
                LC[(t8 + j) * LBSTR + q] = rc[j];
            }
        }

        if (t + 1 < NT) {
            PU[cb ^ 1] = load8(u + ubase + (ss + T) + t8);
            PD[cb ^ 1] = load8(delta + ubase + (ss + T) + t8);
            RB         = load8(Bm + bbase + (ss + T) + t8);
            RC         = load8(Cm + bbase + (ss + T) + t8);
        }

        const float uc[8] = {PU[cb].a.x, PU[cb].a.y, PU[cb].a.z, PU[cb].a.w,
                             PU[cb].b.x, PU[cb].b.y, PU[cb].b.z, PU[cb].b.w};
        const float dc[8] = {
            softplus_f(PD[cb].a.x + sbias), softplus_f(PD[cb].a.y + sbias),
            softplus_f(PD[cb].a.z + sbias), softplus_f(PD[cb].a.w + sbias),
            softplus_f(PD[cb].b.x + sbias), softplus_f(PD[cb].b.y + sbias),
            softplus_f(PD[cb].b.z + sbias), softplus_f(PD[cb].b.w + sbias)};

        float yreg[8];   // lane sub keeps y for its own timesteps t8..t8+7

#define CSTEP(ii) { \
        const float dt  = dpp_qp<(((ii) >> 3) * 0x55)>(dc[(ii) & 7]); \
        const float uu  = dpp_qp<(((ii) >> 3) * 0x55)>(uc[(ii) & 7]); \
        const float dtu = dt * uu; \
        const float4 bv = *(const float4*)(&LB[(ii) * LBSTR + cj]); \
        const float4 cv = *(const float4*)(&LC[(ii) * LBSTR + cj]); \
        x[0] = fmaf(exp2_hw(dt * A2[0]), x[0], dtu * bv.x); \
        x[1] = fmaf(exp2_hw(dt * A2[1]), x[1], dtu * bv.y); \
        x[2] = fmaf(exp2_hw(dt * A2[2]), x[2], dtu * bv.z); \
        x[3] = fmaf(exp2_hw(dt * A2[3]), x[3], dtu * bv.w); \
        float acc = x[0] * cv.x; \
        acc = fmaf(x[1], cv.y, acc); \
        acc = fmaf(x[2], cv.z, acc); \
        acc = fmaf(x[3], cv.w, acc); \
        acc = quad_sum(acc); \
        if (sub == ((ii) >> 3)) yreg[(ii) & 7] = acc; \
    }
        CSTEP(0)  CSTEP(1)  CSTEP(2)  CSTEP(3)
        CSTEP(4)  CSTEP(5)  CSTEP(6)  CSTEP(7)
        CSTEP(8)  CSTEP(9)  CSTEP(10) CSTEP(11)
        CSTEP(12) CSTEP(13) CSTEP(14) CSTEP(15)
        CSTEP(16) CSTEP(17) CSTEP(18) CSTEP(19)
        CSTEP(20) CSTEP(21) CSTEP(22) CSTEP(23)
        CSTEP(24) CSTEP(25) CSTEP(26) CSTEP(27)
        CSTEP(28) CSTEP(29) CSTEP(30) CSTEP(31)
#undef CSTEP

        // fold D*u (lane's own timesteps) and write full 128B per channel row
        yreg[0] = fmaf(Dval, uc[0], yreg[0]);
        yreg[1] = fmaf(Dval, uc[1], yreg[1]);
        yreg[2] = fmaf(Dval, uc[2], yreg[2]);
        yreg[3] = fmaf(Dval, uc[3], yreg[3]);
        yreg[4] = fmaf(Dval, uc[4], yreg[4]);
        yreg[5] = fmaf(Dval, uc[5], yreg[5]);
        yreg[6] = fmaf(Dval, uc[6], yreg[6]);
        yreg[7] = fmaf(Dval, uc[7], yreg[7]);
        *(float4*)(y + ubase + ss + t8)     = make_float4(yreg[0], yreg[1], yreg[2], yreg[3]);
        *(float4*)(y + ubase + ss + t8 + 4) = make_float4(yreg[4], yreg[5], yreg[6], yreg[7]);
    }
}

extern "C" void kernel_launch(void* const* d_in, const int* in_sizes, int n_in,
                              void* d_out, int out_size, void* d_ws, size_t ws_size,
                              hipStream_t stream)
{
    const float* u     = (const float*)d_in[0];
    const float* delta = (const float*)d_in[1];
    const float* Bm    = (const float*)d_in[2];
    const float* Cm    = (const float*)d_in[3];
    const float* A     = (const float*)d_in[4];
    const float* Dv    = (const float*)d_in[5];
    const float* dbias = (const float*)d_in[6];
    float* y = (float*)d_out;

    // workspace: sumdt [NCH*NCHAN] then S/x0 [NCH*NCHAN*NST]  (~13.4 MB)
    float* sumdt = (float*)d_ws;
    float* S     = sumdt + (size_t)NCHAN * NCH;

    const dim3 grid(NCHAN / 64, NCH);
    ssm_phaseA<<<grid, 256, 0, stream>>>(u, delta, Bm, A, dbias, sumdt, S);
    ssm_phaseB<<<(NCHAN * NST) / 256, 256, 0, stream>>>(A, sumdt, S);
    ssm_phaseC<<<grid, 256, 0, stream>>>(u, delta, Bm, Cm, A, Dv, dbias, S, y);
}

// Round 5
// 812.104 us; speedup vs baseline: 1.4371x; 1.4371x over previous
//
#include <hip/hip_runtime.h>

#define BATCH 4
#define DIM   1536
#define SEQ   4096
#define NST   16
#define NCHAN (BATCH*DIM)
#define NCH   32       // chunks per sequence
#define CLEN  128      // chunk length: NCH*CLEN == SEQ
#define T     16       // timesteps per staged subtile (64B per row per access)
#define LBSTR 20       // LDS B/C tile stride ([t][n], padded: write conflicts <=2-way)

#define LOG2E 1.4426950408889634f

// softplus matching jax.nn.softplus = log1p(exp(z)), overflow-safe
__device__ __forceinline__ float softplus_f(float z) {
    return (z > 20.f) ? z : __logf(1.f + __expf(z));
}
__device__ __forceinline__ float exp2_hw(float z) {
    return __builtin_amdgcn_exp2f(z);
}

// DPP quad_perm helper (compile-time control). All lanes active, uniform flow.
template<int CTRL>
__device__ __forceinline__ float dpp_qp(float v) {
    return __int_as_float(
        __builtin_amdgcn_mov_dpp(__float_as_int(v), CTRL, 0xf, 0xf, true));
}
// sum across the 4 lanes of a quad (result in all 4 lanes)
__device__ __forceinline__ float quad_sum(float v) {
    v += dpp_qp<0xB1>(v);   // quad_perm [1,0,3,2]
    v += dpp_qp<0x4E>(v);   // quad_perm [2,3,0,1]
    return v;
}

// ---------------------------------------------------------------------------
// Round-2 structure (verified best: 537us total), single change: launch
// bounds (256,6) -> (256,8). Grid supplies 12 blocks/CU; VGPR(40) and LDS
// (10KB) both permit 8 blocks/CU; the old bound capped residency at 6.
// ---------------------------------------------------------------------------

// ---------------- Phase A: per-(channel,chunk) summaries ----------------
__global__ __launch_bounds__(256, 8) void ssm_phaseA(
    const float* __restrict__ u, const float* __restrict__ delta,
    const float* __restrict__ Bm, const float* __restrict__ A,
    const float* __restrict__ dbias,
    float* __restrict__ sumdt_out, float* __restrict__ S_out)
{
    __shared__ float lB[4 * T * LBSTR];

    const int tid = threadIdx.x;
    const int w   = tid >> 6;
    const int l   = tid & 63;
    const int q   = l >> 2;      // quad index = channel row in wave = B state row
    const int sub = l & 3;       // lane within quad: owns states sub*4..+3
    const int cj  = sub << 2;    // this lane's 4-timestep column slot in a tile

    const int ch0 = blockIdx.x * 64;
    const int ch  = ch0 + w * 16 + q;
    const int d   = ch % DIM;
    const int bb  = ch0 / DIM;   // batch (64 | 1536, no straddle)
    const int k   = blockIdx.y;
    const int s0  = k * CLEN;

    float* LB = &lB[w * T * LBSTR];

    float A2[4];
    {
        const float4 av = *(const float4*)(A + (size_t)d * NST + sub * 4);
        A2[0] = av.x * LOG2E; A2[1] = av.y * LOG2E;
        A2[2] = av.z * LOG2E; A2[3] = av.w * LOG2E;
    }
    const float sbias = dbias[d];

    const size_t ubase = (size_t)ch * SEQ + s0;
    const size_t bbase = ((size_t)bb * NST + q) * SEQ + s0;

    float4 run = *(const float4*)(u + ubase + cj);
    float4 rdn = *(const float4*)(delta + ubase + cj);
    float4 rbn = *(const float4*)(Bm + bbase + cj);

    float S[4] = {0.f, 0.f, 0.f, 0.f};
    float sumdt = 0.f;

    for (int ss = 0; ss < CLEN; ss += T) {
        // unpack current tile into register arrays (static indexing only)
        const float uc[4] = {run.x, run.y, run.z, run.w};
        const float dc[4] = {softplus_f(rdn.x + sbias), softplus_f(rdn.y + sbias),
                             softplus_f(rdn.z + sbias), softplus_f(rdn.w + sbias)};
        sumdt += (dc[0] + dc[1]) + (dc[2] + dc[3]);

        // stage B tile [t][n] (4 scatter writes, <=2-way bank alias with LBSTR=20)
        LB[(cj + 0) * LBSTR + q] = rbn.x;
        LB[(cj + 1) * LBSTR + q] = rbn.y;
        LB[(cj + 2) * LBSTR + q] = rbn.z;
        LB[(cj + 3) * LBSTR + q] = rbn.w;

        // prefetch next tile (64B per row, sector-aligned)
        if (ss + T < CLEN) {
            run = *(const float4*)(u + ubase + (ss + T) + cj);
            rdn = *(const float4*)(delta + ubase + (ss + T) + cj);
            rbn = *(const float4*)(Bm + bbase + (ss + T) + cj);
        }

#define ASTEP(ii) { \
        const float dt  = dpp_qp<(((ii) >> 2) * 0x55)>(dc[(ii) & 3]); \
        const float uu  = dpp_qp<(((ii) >> 2) * 0x55)>(uc[(ii) & 3]); \
        const float dtu = dt * uu; \
        const float4 bv = *(const float4*)(&LB[(ii) * LBSTR + cj]); \
        S[0] = fmaf(exp2_hw(dt * A2[0]), S[0], dtu * bv.x); \
        S[1] = fmaf(exp2_hw(dt * A2[1]), S[1], dtu * bv.y); \
        S[2] = fmaf(exp2_hw(dt * A2[2]), S[2], dtu * bv.z); \
        S[3] = fmaf(exp2_hw(dt * A2[3]), S[3], dtu * bv.w); \
    }
        ASTEP(0)  ASTEP(1)  ASTEP(2)  ASTEP(3)
        ASTEP(4)  ASTEP(5)  ASTEP(6)  ASTEP(7)
        ASTEP(8)  ASTEP(9)  ASTEP(10) ASTEP(11)
        ASTEP(12) ASTEP(13) ASTEP(14) ASTEP(15)
#undef ASTEP
    }

    // S: lane writes its 4 states; quad writes 64B contiguous
    *(float4*)(S_out + ((size_t)k * NCHAN + ch) * NST + sub * 4) =
        make_float4(S[0], S[1], S[2], S[3]);

    const float sfull = quad_sum(sumdt);
    if (sub == 0) sumdt_out[(size_t)k * NCHAN + ch] = sfull;
}

// ---------------- Phase B: scan chunk summaries -> chunk entry states ----
// In-place on S[k][ch][n]: becomes x0 (state entering chunk k). Pipelined.
__global__ __launch_bounds__(256) void ssm_phaseB(
    const float* __restrict__ A, const float* __restrict__ sumdt,
    float* __restrict__ S)
{
    const int t  = blockIdx.x * 256 + threadIdx.x;
    const int n  = t & 15;
    const int ch = t >> 4;
    if (ch >= NCHAN) return;
    const int d = ch % DIM;
    const float An2 = A[(size_t)d * NST + n] * LOG2E;

    const size_t kstride = (size_t)NCHAN * NST;
    size_t idx = (size_t)ch * NST + n;

    float x = 0.f;
    float s_nxt = S[idx];
    float p_nxt = sumdt[ch];
#pragma unroll 4
    for (int k = 0; k < NCH; k++) {
        const float s_old = s_nxt;
        const float pdt   = p_nxt;
        if (k + 1 < NCH) {
            s_nxt = S[idx + kstride];
            p_nxt = sumdt[(size_t)(k + 1) * NCHAN + ch];
        }
        S[idx] = x;                                   // x0 for chunk k
        x = fmaf(exp2_hw(An2 * pdt), x, s_old);       // state after chunk k
        idx += kstride;
    }
}

// ---------------- Phase C: replay chunk from x0, emit y ------------------
__global__ __launch_bounds__(256, 8) void ssm_phaseC(
    const float* __restrict__ u, const float* __restrict__ delta,
    const float* __restrict__ Bm, const float* __restrict__ Cm,
    const float* __restrict__ A, const float* __restrict__ Dv,
    const float* __restrict__ dbias, const float* __restrict__ x0,
    float* __restrict__ y)
{
    __shared__ float lB[4 * T * LBSTR];
    __shared__ float lC[4 * T * LBSTR];

    const int tid = threadIdx.x;
    const int w   = tid >> 6;
    const int l   = tid & 63;
    const int q   = l >> 2;
    const int sub = l & 3;
    const int cj  = sub << 2;

    const int ch0 = blockIdx.x * 64;
    const int ch  = ch0 + w * 16 + q;
    const int d   = ch % DIM;
    const int bb  = ch0 / DIM;
    const int k   = blockIdx.y;
    const int s0  = k * CLEN;

    float* LB = &lB[w * T * LBSTR];
    float* LC = &lC[w * T * LBSTR];

    float A2[4];
    {
        const float4 av = *(const float4*)(A + (size_t)d * NST + sub * 4);
        A2[0] = av.x * LOG2E; A2[1] = av.y * LOG2E;
        A2[2] = av.z * LOG2E; A2[3] = av.w * LOG2E;
    }
    const float sbias = dbias[d];
    const float Dval  = Dv[d];

    float x[4];
    {
        const float4 xv = *(const float4*)(x0 + ((size_t)k * NCHAN + ch) * NST + sub * 4);
        x[0] = xv.x; x[1] = xv.y; x[2] = xv.z; x[3] = xv.w;
    }

    const size_t ubase = (size_t)ch * SEQ + s0;
    const size_t bbase = ((size_t)bb * NST + q) * SEQ + s0;

    float4 run = *(const float4*)(u + ubase + cj);
    float4 rdn = *(const float4*)(delta + ubase + cj);
    float4 rbn = *(const float4*)(Bm + bbase + cj);
    float4 rcn = *(const float4*)(Cm + bbase + cj);

    for (int ss = 0; ss < CLEN; ss += T) {
        const float uc[4] = {run.x, run.y, run.z, run.w};
        const float dc[4] = {softplus_f(rdn.x + sbias), softplus_f(rdn.y + sbias),
                             softplus_f(rdn.z + sbias), softplus_f(rdn.w + sbias)};

        LB[(cj + 0) * LBSTR + q] = rbn.x;
        LB[(cj + 1) * LBSTR + q] = rbn.y;
        LB[(cj + 2) * LBSTR + q] = rbn.z;
        LB[(cj + 3) * LBSTR + q] = rbn.w;
        LC[(cj + 0) * LBSTR + q] = rcn.x;
        LC[(cj + 1) * LBSTR + q] = rcn.y;
        LC[(cj + 2) * LBSTR + q] = rcn.z;
        LC[(cj + 3) * LBSTR + q] = rcn.w;

        if (ss + T < CLEN) {
            run = *(const float4*)(u + ubase + (ss + T) + cj);
            rdn = *(const float4*)(delta + ubase + (ss + T) + cj);
            rbn = *(const float4*)(Bm + bbase + (ss + T) + cj);
            rcn = *(const float4*)(Cm + bbase + (ss + T) + cj);
        }

        float yreg[4];   // lane sub keeps y for timesteps sub*4..sub*4+3

#define CSTEP(ii) { \
        const float dt  = dpp_qp<(((ii) >> 2) * 0x55)>(dc[(ii) & 3]); \
        const float uu  = dpp_qp<(((ii) >> 2) * 0x55)>(uc[(ii) & 3]); \
        const float dtu = dt * uu; \
        const float4 bv = *(const float4*)(&LB[(ii) * LBSTR + cj]); \
        const float4 cv = *(const float4*)(&LC[(ii) * LBSTR + cj]); \
        x[0] = fmaf(exp2_hw(dt * A2[0]), x[0], dtu * bv.x); \
        x[1] = fmaf(exp2_hw(dt * A2[1]), x[1], dtu * bv.y); \
        x[2] = fmaf(exp2_hw(dt * A2[2]), x[2], dtu * bv.z); \
        x[3] = fmaf(exp2_hw(dt * A2[3]), x[3], dtu * bv.w); \
        float acc = x[0] * cv.x; \
        acc = fmaf(x[1], cv.y, acc); \
        acc = fmaf(x[2], cv.z, acc); \
        acc = fmaf(x[3], cv.w, acc); \
        acc = quad_sum(acc); \
        const float yv = fmaf(Dval, uu, acc); \
        if (sub == ((ii) >> 2)) yreg[(ii) & 3] = yv; \
    }
        CSTEP(0)  CSTEP(1)  CSTEP(2)  CSTEP(3)
        CSTEP(4)  CSTEP(5)  CSTEP(6)  CSTEP(7)
        CSTEP(8)  CSTEP(9)  CSTEP(10) CSTEP(11)
        CSTEP(12) CSTEP(13) CSTEP(14) CSTEP(15)
#undef CSTEP

        // quad writes 64B contiguous of this channel's y row
        *(float4*)(y + ubase + ss + sub * 4) =
            make_float4(yreg[0], yreg[1], yreg[2], yreg[3]);
    }
}

extern "C" void kernel_launch(void* const* d_in, const int* in_sizes, int n_in,
                              void* d_out, int out_size, void* d_ws, size_t ws_size,
                              hipStream_t stream)
{
    const float* u     = (const float*)d_in[0];
    const float* delta = (const float*)d_in[1];
    const float* Bm    = (const float*)d_in[2];
    const float* Cm    = (const float*)d_in[3];
    const float* A     = (const float*)d_in[4];
    const float* Dv    = (const float*)d_in[5];
    const float* dbias = (const float*)d_in[6];
    float* y = (float*)d_out;

    // workspace: sumdt [NCH*NCHAN] then S/x0 [NCH*NCHAN*NST]  (~13.4 MB total)
    float* sumdt = (float*)d_ws;
    float* S     = sumdt + (size_t)NCHAN * NCH;

    const dim3 grid(NCHAN / 64, NCH);
    ssm_phaseA<<<grid, 256, 0, stream>>>(u, delta, Bm, A, dbias, sumdt, S);
    ssm_phaseB<<<(NCHAN * NST) / 256, 256, 0, stream>>>(A, sumdt, S);
    ssm_phaseC<<<grid, 256, 0, stream>>>(u, delta, Bm, Cm, A, Dv, dbias, S, y);
}